// Round 22
// baseline (176.672 us; speedup 1.0000x reference)
//
#include <hip/hip_runtime.h>
#include <hip/hip_bf16.h>

typedef unsigned short u16;
typedef __attribute__((ext_vector_type(8))) short bf16x8;   // 8 bf16 = 4 VGPRs (MFMA A/B frag)
typedef __attribute__((ext_vector_type(4))) float f32x4;    // MFMA C/D frag
typedef __attribute__((ext_vector_type(4))) unsigned u32x4;

#define L2E 1.4426950408889634f

__device__ __forceinline__ u16 f2bf(float f) {
  unsigned u = __float_as_uint(f);
  u = u + 0x7fffu + ((u >> 16) & 1u);   // RNE
  return (u16)(u >> 16);
}
__device__ __forceinline__ unsigned cvtpk(float a, float b) {  // low = bf16(a), high = bf16(b), HW RNE
  unsigned r;
  asm("v_cvt_pk_bf16_f32 %0, %1, %2" : "=v"(r) : "v"(a), "v"(b));
  return r;
}
__device__ __forceinline__ float lo16(unsigned v) { return __uint_as_float(v << 16); }
__device__ __forceinline__ float hi16(unsigned v) { return __uint_as_float(v & 0xffff0000u); }

// ---------------- prep: W[k][n] f32 -> Wt[n][k] bf16 (3 weights via blockIdx.z) ----------------
__global__ void wtrans3(const float* __restrict__ Wq, const float* __restrict__ Wk,
                        const float* __restrict__ Wv,
                        u16* __restrict__ Wtq, u16* __restrict__ Wtk, u16* __restrict__ Wtv) {
  int z = blockIdx.z;
  const float* W = (z == 0) ? Wq : (z == 1) ? Wk : Wv;
  u16* Wt = (z == 0) ? Wtq : (z == 1) ? Wtk : Wtv;
  __shared__ float T[32][33];
  int k0 = blockIdx.y * 32, n0 = blockIdx.x * 32;
  int tx = threadIdx.x, ty = threadIdx.y;       // (32,8)
  #pragma unroll
  for (int j = 0; j < 4; ++j) T[ty + 8*j][tx] = W[(size_t)(k0 + ty + 8*j) * 1024 + n0 + tx];
  __syncthreads();
  #pragma unroll
  for (int j = 0; j < 4; ++j) Wt[(size_t)(n0 + ty + 8*j) * 1024 + k0 + tx] = f2bf(T[tx][ty + 8*j]);
}

// ---------------- QKV projection GEMM, BK=64 (1D grid, XCD-aware decode) ----------------
// R20 structure with the K-tile doubled to 64 (barriers 32 -> 16, each covering
// 32 MFMAs). The [128 rows][64 k] chunk-swizzle reuses attn16's battle-tested
// layout: F(row) = (row&3)|(((row>>3)^(row>>4))&1)<<2; frag chunks (g^F), ((g+4)^F).
// A: reg-staged f32->bf16 (1-deep prefetch, cover = full 64-k step); B: global_load_lds.
// LDS 64 KB -> 2 blocks/CU (register file already binds there; m132 lesson avoided).
// grid 1536 = 8 xcd x 24 (z,y) x 8 n-blocks; z==2 writes V^T.
__global__ __launch_bounds__(256) void qkv_gemm3(const float* __restrict__ S1, const float* __restrict__ S2,
                                                 const u16* __restrict__ Wtq, const u16* __restrict__ Wtk,
                                                 const u16* __restrict__ Wtv,
                                                 const float* __restrict__ bq, const float* __restrict__ bk,
                                                 const float* __restrict__ bv,
                                                 u16* __restrict__ Qo, u16* __restrict__ Ko, u16* __restrict__ Vo) {
  int bid = blockIdx.x;
  int xcd = bid & 7, idx = bid >> 3;
  int nblk = idx & 7, pair = idx >> 3;
  int zy = xcd * 24 + pair;          // [0,192): 24 (z,y) pairs per XCD
  int z = zy >> 6, y = zy & 63;
  int m0 = y * 128, n0 = nblk * 128;

  const float* Xf  = (z == 0) ? S1 : S2;
  const u16* Wt  = (z == 0) ? Wtq : (z == 1) ? Wtk : Wtv;
  const float* bias = (z == 0) ? bq : (z == 1) ? bk : bv;
  u16* outp = (z == 0) ? Qo : (z == 1) ? Ko : Vo;

  __shared__ __align__(16) u16 As[2][8192];   // [128 rows][64 k], attn-style chunk swizzle
  __shared__ __align__(16) u16 Bs[2][8192];
  int tid = threadIdx.x;
  int w = tid >> 6, l = tid & 63;
  int wm = w >> 1, wn = w & 1;
  int lq = l & 15, g = l >> 4;
  const int4* Ws = (const int4*)Wt;

  // A chunk descriptors: chunk i_=(row_ 0..127, ch_ 0..7); src k-chunk = ch_ ^ F(row_)
  const float4* aSrc[4]; int aDst[4];
  const int4* bSrc[4]; int bDst[4];
  #pragma unroll
  for (int c_ = 0; c_ < 4; ++c_) {
    int i_ = c_ * 256 + tid;
    int row_ = i_ >> 3, ch_ = i_ & 7;
    int f_ = (row_ & 3) | ((((row_ >> 3) ^ (row_ >> 4)) & 1) << 2);
    aSrc[c_] = (const float4*)(Xf + (size_t)(m0 + row_) * 1024) + (ch_ ^ f_) * 2;  // +kt*16 float4s
    aDst[c_] = i_ * 8;                                                             // u16 offset
    bSrc[c_] = (const int4*)Ws + (size_t)(n0 + row_) * 128 + (ch_ ^ f_);           // +kt*8 int4s
    bDst[c_] = i_;                                                                 // int4 index
  }

#define BSTAGE(bi, kt) do { _Pragma("unroll")                                                \
    for (int c_ = 0; c_ < 4; ++c_)                                                          \
      __builtin_amdgcn_global_load_lds(                                                     \
          (const __attribute__((address_space(1))) void*)(bSrc[c_] + (kt) * 8),             \
          (__attribute__((address_space(3))) void*)&((int4*)Bs[bi])[bDst[c_]], 16, 0, 0);   \
    } while (0)

#define ALOAD(kt) do { _Pragma("unroll")                                                    \
    for (int c_ = 0; c_ < 4; ++c_) {                                                        \
      xa[c_][0] = aSrc[c_][(kt) * 16];                                                      \
      xa[c_][1] = aSrc[c_][(kt) * 16 + 1];                                                  \
    } } while (0)

#define AWRITE(bi) do { _Pragma("unroll")                                                   \
    for (int c_ = 0; c_ < 4; ++c_) {                                                        \
      u32x4 pk_;                                                                            \
      pk_[0] = cvtpk(xa[c_][0].x, xa[c_][0].y);                                             \
      pk_[1] = cvtpk(xa[c_][0].z, xa[c_][0].w);                                             \
      pk_[2] = cvtpk(xa[c_][1].x, xa[c_][1].y);                                             \
      pk_[3] = cvtpk(xa[c_][1].z, xa[c_][1].w);                                             \
      *(u32x4*)&As[bi][aDst[c_]] = pk_;                                                     \
    } } while (0)

  // hoisted swizzled frag offsets (attn16 pattern): sub-tile c in {0,1} -> chunks (c*4+g)^F
  int aOff[4][2], bOff[4][2];
  #pragma unroll
  for (int mc = 0; mc < 4; ++mc) {
    int rowA = wm * 64 + mc * 16 + lq;
    int FA = (rowA & 3) | ((((rowA >> 3) ^ (rowA >> 4)) & 1) << 2);
    aOff[mc][0] = rowA * 64 + ((g ^ FA) * 8);
    aOff[mc][1] = rowA * 64 + (((g + 4) ^ FA) * 8);
    int rowB = wn * 64 + mc * 16 + lq;
    int FB = (rowB & 3) | ((((rowB >> 3) ^ (rowB >> 4)) & 1) << 2);
    bOff[mc][0] = rowB * 64 + ((g ^ FB) * 8);
    bOff[mc][1] = rowB * 64 + (((g + 4) ^ FB) * 8);
  }

#define MFMA32(bi) do { _Pragma("unroll")                                                   \
    for (int c_ = 0; c_ < 2; ++c_) {                                                        \
      bf16x8 a_[4], bb_[4];                                                                 \
      _Pragma("unroll")                                                                     \
      for (int mc = 0; mc < 4; ++mc) a_[mc]  = *(const bf16x8*)&As[bi][aOff[mc][c_]];       \
      _Pragma("unroll")                                                                     \
      for (int nc = 0; nc < 4; ++nc) bb_[nc] = *(const bf16x8*)&Bs[bi][bOff[nc][c_]];       \
      __builtin_amdgcn_s_setprio(1);                                                        \
      _Pragma("unroll")                                                                     \
      for (int mc = 0; mc < 4; ++mc)                                                        \
        _Pragma("unroll")                                                                   \
        for (int nc = 0; nc < 4; ++nc)                                                      \
          acc[mc][nc] = __builtin_amdgcn_mfma_f32_16x16x32_bf16(a_[mc], bb_[nc], acc[mc][nc], 0, 0, 0); \
      __builtin_amdgcn_s_setprio(0);                                                        \
    } } while (0)

  f32x4 acc[4][4] = {};
  float4 xa[4][2];
  // prologue: stage tile 0
  ALOAD(0);
  BSTAGE(0, 0);
  AWRITE(0);
  __syncthreads();
  int cur = 0;
  for (int kt = 0; kt < 16; ++kt) {
    if (kt < 15) {                          // issue next-tile loads early (cover = full step)
      ALOAD(kt + 1);
      BSTAGE(cur ^ 1, kt + 1);
    }
    MFMA32(cur);
    if (kt < 15) AWRITE(cur ^ 1);           // convert+write late (loads landed under 32 MFMAs)
    __syncthreads();                        // drains vmcnt+lgkmcnt -> tile kt+1 visible
    cur ^= 1;
  }
#undef BSTAGE
#undef ALOAD
#undef AWRITE
#undef MFMA32
  #pragma unroll
  for (int nc = 0; nc < 4; ++nc) {
    int n = n0 + wn * 64 + nc * 16 + lq;
    float bvv = bias[n];
    int h = n >> 6, d = n & 63;
    #pragma unroll
    for (int mc = 0; mc < 4; ++mc) {
      int srow_base = m0 + wm * 64 + mc * 16 + g * 4;
      if (z == 2) {
        int b = srow_base >> 10, s = srow_base & 1023;   // srow_base % 4 == 0, no b-crossing in r
        ushort4 vv;
        vv.x = f2bf(acc[mc][nc][0] + bvv);
        vv.y = f2bf(acc[mc][nc][1] + bvv);
        vv.z = f2bf(acc[mc][nc][2] + bvv);
        vv.w = f2bf(acc[mc][nc][3] + bvv);
        *(ushort4*)&outp[((size_t)((b * 16 + h) * 64 + d)) * 1024 + s] = vv;
      } else {
        #pragma unroll
        for (int r = 0; r < 4; ++r) {
          int sm = srow_base + r;
          int b = sm >> 10, s = sm & 1023;
          outp[((size_t)((b * 16 + h) * 1024 + s)) * 64 + d] = f2bf(acc[mc][nc][r] + bvv);
        }
      }
    }
  }
}

// ---------------- fused double-softmax attention, v17 (frozen from R21, passing) ----------------
__global__ __launch_bounds__(256, 2) void attn17(const u16* __restrict__ Q, const u16* __restrict__ K,
                                                 const u16* __restrict__ Vt, const float* __restrict__ mask,
                                                 const int* __restrict__ clp, float* __restrict__ out) {
  __shared__ __align__(16) u16 KVl[2][8192];   // pass A: K dbuf; pass B: V dbuf; epilogue: redF
  __shared__ __align__(16) float maskL2[1024]; // mask * log2e
  __shared__ float z1p[4][32];
  __shared__ float z2p[4][32];

  int bid = blockIdx.x;
  int xcd = bid & 7, idx = bid >> 3;
  int bh = xcd * 16 + (idx >> 5);   // 32 q-tile blocks share (b,h) within an XCD
  int qt = idx & 31;
  int b = bh >> 4, h = bh & 15;
  int tid = threadIdx.x;
  int w = tid >> 6, l = tid & 63;
  int lq = l & 15, g = l >> 4;
  int qb = qt * 32;

  const u16* Kb = K + (size_t)bh * 65536;
  const u16* Vb = Vt + (size_t)bh * 65536;
  int cl = clp[0];

  // ---- hoisted staging addresses (affine in t) ----
  const u16* kS[4]; int kD[4];
  #pragma unroll
  for (int c_ = 0; c_ < 4; ++c_) {
    int i_ = c_ * 256 + tid, row_ = i_ >> 3, ch_ = i_ & 7;
    int f_ = (row_ & 3) | ((((row_ >> 3) ^ (row_ >> 4)) & 1) << 2);
    kS[c_] = Kb + row_ * 64 + (ch_ ^ f_) * 8;
    kD[c_] = i_ * 8;
  }
  const u16* vS[4]; int vD[4];
  #pragma unroll
  for (int c_ = 0; c_ < 4; ++c_) {
    int i_ = c_ * 256 + tid, row_ = i_ >> 4, ch_ = i_ & 15;
    vS[c_] = Vb + row_ * 1024 + (ch_ ^ (row_ & 15)) * 8;
    vD[c_] = i_ * 8;
  }

#define STAGE_K(bi, t) do { _Pragma("unroll")                                                 \
    for (int c_ = 0; c_ < 4; ++c_)                                                           \
      __builtin_amdgcn_global_load_lds(                                                      \
        (const __attribute__((address_space(1))) void*)(kS[c_] + (t) * 8192),                \
        (__attribute__((address_space(3))) void*)&KVl[bi][kD[c_]], 16, 0, 0); } while (0)

#define STAGE_V(bi, t) do { _Pragma("unroll")                                                 \
    for (int c_ = 0; c_ < 4; ++c_)                                                           \
      __builtin_amdgcn_global_load_lds(                                                      \
        (const __attribute__((address_space(1))) void*)(vS[c_] + (t) * 128),                 \
        (__attribute__((address_space(3))) void*)&KVl[bi][vD[c_]], 16, 0, 0); } while (0)

  STAGE_K(0, 0);

  for (int i = tid; i < 1024; i += 256) maskL2[i] = mask[b * 1024 + i] * L2E;

  // Q fragments: 32 rows (qg 0,1)
  bf16x8 qf[2][2];
  #pragma unroll
  for (int qg = 0; qg < 2; ++qg) {
    const u16* Qp = Q + ((size_t)bh * 1024 + qb + qg * 16 + lq) * 64 + g * 8;
    qf[qg][0] = *(const bf16x8*)Qp;
    qf[qg][1] = *(const bf16x8*)(Qp + 32);
  }

  // ---- hoisted LDS read offsets (lane-constant) ----
  int kOff[2][2];
  #pragma unroll
  for (int c = 0; c < 2; ++c) {
    int row128 = w * 32 + ((lq >> 2) << 3) + c * 4 + (lq & 3);   // kappa(A-row = lq)
    int F = (row128 & 3) | ((((row128 >> 3) ^ (row128 >> 4)) & 1) << 2);
    kOff[c][0] = row128 * 64 + ((g ^ F) * 8);
    kOff[c][1] = row128 * 64 + (((g + 4) ^ F) * 8);
  }
  int vOff[4];
  #pragma unroll
  for (int dc = 0; dc < 4; ++dc) {
    int row = dc * 16 + lq;
    vOff[dc] = row * 128 + (((w * 4 + g) ^ (row & 15)) * 8);
  }
  int mBase = w * 32 + g * 8;   // mask index = t*128 + mBase + c*4

  __syncthreads();   // K0 staged + maskL2 ready

  // ---- pass A: swapped QK^T (quarter x 32q), E = exp2(s+mkl) packed to sp[64], Z1 ----
  const float sl2e = 0.125f * L2E;
  unsigned sp[64];
  float z1[2] = {0.f, 0.f};
  int cur = 0;
  #pragma unroll
  for (int t = 0; t < 8; ++t) {
    if (t < 7) STAGE_K(cur ^ 1, t + 1);
    else       STAGE_V(0, 0);            // prefetch pass-B V tile 0 (KVl[0] dead: cur==1 at t=7)
    #pragma unroll
    for (int c = 0; c < 2; ++c) {
      bf16x8 kf0 = *(const bf16x8*)&KVl[cur][kOff[c][0]];
      bf16x8 kf1 = *(const bf16x8*)&KVl[cur][kOff[c][1]];
      const float4 mk = *(const float4*)&maskL2[t * 128 + mBase + c * 4];
      #pragma unroll
      for (int qg = 0; qg < 2; ++qg) {
        f32x4 tt = {0.f, 0.f, 0.f, 0.f};
        __builtin_amdgcn_s_setprio(1);
        tt = __builtin_amdgcn_mfma_f32_16x16x32_bf16(kf0, qf[qg][0], tt, 0, 0, 0);
        tt = __builtin_amdgcn_mfma_f32_16x16x32_bf16(kf1, qf[qg][1], tt, 0, 0, 0);
        __builtin_amdgcn_s_setprio(0);
        float e0 = __builtin_amdgcn_exp2f(fmaf(tt[0], sl2e, mk.x));
        float e1 = __builtin_amdgcn_exp2f(fmaf(tt[1], sl2e, mk.y));
        float e2 = __builtin_amdgcn_exp2f(fmaf(tt[2], sl2e, mk.z));
        float e3 = __builtin_amdgcn_exp2f(fmaf(tt[3], sl2e, mk.w));
        z1[qg] += (e0 + e1) + (e2 + e3);
        sp[t * 8 + qg * 4 + c * 2 + 0] = cvtpk(e0, e1);
        sp[t * 8 + qg * 4 + c * 2 + 1] = cvtpk(e2, e3);
      }
    }
    __syncthreads();
    cur ^= 1;
  }

  // ---- merge Z1: g-groups (shfl) + 4 waves (LDS) -> cr[qg] = L2E / Z1 ----
  #pragma unroll
  for (int qg = 0; qg < 2; ++qg) {
    z1[qg] += __shfl_xor(z1[qg], 16);
    z1[qg] += __shfl_xor(z1[qg], 32);
  }
  if (l < 16) { z1p[w][l] = z1[0]; z1p[w][16 + l] = z1[1]; }
  __syncthreads();
  float cr[2];
  #pragma unroll
  for (int qg = 0; qg < 2; ++qg) {
    int q = qg * 16 + lq;
    float Z1 = (z1p[0][q] + z1p[1][q]) + (z1p[2][q] + z1p[3][q]);
    cr[qg] = L2E * __builtin_amdgcn_rcpf(Z1);
  }

  // ---- pass B: p2 = exp2(mkl - cr*E), PV over V dbuf (tile t in KVl[t&1]) ----
  f32x4 acc[2][4] = {};
  float z2[2] = {0.f, 0.f};
  #pragma unroll
  for (int t = 0; t < 8; ++t) {
    if (t < 7) STAGE_V((t + 1) & 1, t + 1);
    u32x4 pk[2];
    #pragma unroll
    for (int qg = 0; qg < 2; ++qg) {
      if (cl) {
        #pragma unroll
        for (int j = 0; j < 4; ++j) {
          unsigned e = sp[t * 8 + qg * 4 + j];
          float mkA = maskL2[t * 128 + mBase + 2 * j];
          float mkB = maskL2[t * 128 + mBase + 2 * j + 1];
          float pA = __builtin_amdgcn_exp2f(fmaf(-cr[qg], lo16(e), mkA));
          float pB = __builtin_amdgcn_exp2f(fmaf(-cr[qg], hi16(e), mkB));
          z2[qg] += pA + pB;
          pk[qg][j] = cvtpk(pA, pB);
        }
      } else {
        pk[qg] = *(u32x4*)&sp[t * 8 + qg * 4];   // unnormalized E; epilogue scales by 1/Z1
      }
    }
    __builtin_amdgcn_s_setprio(1);
    #pragma unroll
    for (int dc = 0; dc < 4; ++dc) {
      bf16x8 vf = *(const bf16x8*)&KVl[t & 1][vOff[dc]];
      #pragma unroll
      for (int qg = 0; qg < 2; ++qg)
        acc[qg][dc] = __builtin_amdgcn_mfma_f32_16x16x32_bf16(
            __builtin_bit_cast(bf16x8, pk[qg]), vf, acc[qg][dc], 0, 0, 0);
    }
    __builtin_amdgcn_s_setprio(0);
    if (t < 7) __syncthreads();            // tile t reads done + tile t+1 staged/visible
  }

  // ---- epilogue: 4-way Z2 merge + 4-way acc reduction through dead KVl ----
  #pragma unroll
  for (int qg = 0; qg < 2; ++qg) {
    z2[qg] += __shfl_xor(z2[qg], 16);
    z2[qg] += __shfl_xor(z2[qg], 32);
  }
  if (l < 16) { z2p[w][l] = z2[0]; z2p[w][16 + l] = z2[1]; }
  __syncthreads();   // all waves' V-tile-7 reads (KVl[1]) complete before redF
                     // (26112 B, spans KVl[0]+into KVl[1]) is written.
  float* redF = (float*)&KVl[0][0];    // [3][32 q][68 d-stride]
  if (w > 0) {
    #pragma unroll
    for (int qg = 0; qg < 2; ++qg)
      #pragma unroll
      for (int dc = 0; dc < 4; ++dc)
        #pragma unroll
        for (int r = 0; r < 4; ++r)
          redF[(w - 1) * 2176 + (qg * 16 + g * 4 + r) * 68 + dc * 16 + lq] = acc[qg][dc][r];
  }
  __syncthreads();
  if (w == 0) {
    #pragma unroll
    for (int qg = 0; qg < 2; ++qg) {
      #pragma unroll
      for (int r = 0; r < 4; ++r) {
        int q = qg * 16 + g * 4 + r;
        float phi;
        if (cl) {
          float Z2 = (z2p[0][q] + z2p[1][q]) + (z2p[2][q] + z2p[3][q]);
          phi = __builtin_amdgcn_rcpf(Z2);
        } else {
          float Z1 = (z1p[0][q] + z1p[1][q]) + (z1p[2][q] + z1p[3][q]);
          phi = __builtin_amdgcn_rcpf(Z1);
        }
        size_t orow = ((size_t)(b * 1024 + qb + q)) * 1024 + h * 64;
        #pragma unroll
        for (int dc = 0; dc < 4; ++dc) {
          int dq = q * 68 + dc * 16 + lq;
          float o = acc[qg][dc][r] + redF[dq] + redF[2176 + dq] + redF[4352 + dq];
          out[orow + dc * 16 + lq] = o * phi;
        }
      }
    }
  }
#undef STAGE_K
#undef STAGE_V
}

extern "C" void kernel_launch(void* const* d_in, const int* in_sizes, int n_in,
                              void* d_out, int out_size, void* d_ws, size_t ws_size,
                              hipStream_t stream) {
  const float* s1   = (const float*)d_in[0];
  const float* s2   = (const float*)d_in[1];
  const float* mask = (const float*)d_in[2];
  const float* Wq   = (const float*)d_in[3];
  const float* bq   = (const float*)d_in[4];
  const float* Wk   = (const float*)d_in[5];
  const float* bk   = (const float*)d_in[6];
  const float* Wv   = (const float*)d_in[7];
  const float* bv   = (const float*)d_in[8];
  const int*   cl   = (const int*)d_in[9];
  float* out = (float*)d_out;

  // ws layout (u16 elements): [unused 16M] Wtq[1M] Wtk[1M] Wtv[1M] Q[8M] K[8M] Vt[8M]
  u16* ws  = (u16*)d_ws;
  const size_t M1 = 1024 * 1024;
  u16* Wtq = ws + 16 * M1;
  u16* Wtk = Wtq + M1;
  u16* Wtv = Wtk + M1;
  u16* Qb  = Wtv + M1;
  u16* Kb  = Qb + 8 * M1;
  u16* Vtb = Kb + 8 * M1;        // V^T written directly by qkv_gemm3 (z==2)

  wtrans3<<<dim3(32, 32, 3), dim3(32, 8), 0, stream>>>(Wq, Wk, Wv, Wtq, Wtk, Wtv);
  qkv_gemm3<<<1536, 256, 0, stream>>>(s1, s2, Wtq, Wtk, Wtv, bq, bk, bv, Qb, Kb, Vtb);
  attn17<<<4096, 256, 0, stream>>>(Qb, Kb, Vtb, mask, cl, out);
}

// Round 23
// 171.574 us; speedup vs baseline: 1.0297x; 1.0297x over previous
//
#include <hip/hip_runtime.h>
#include <hip/hip_bf16.h>

typedef unsigned short u16;
typedef __attribute__((ext_vector_type(8))) short bf16x8;   // 8 bf16 = 4 VGPRs (MFMA A/B frag)
typedef __attribute__((ext_vector_type(4))) float f32x4;    // MFMA C/D frag
typedef __attribute__((ext_vector_type(4))) unsigned u32x4;

#define L2E 1.4426950408889634f

__device__ __forceinline__ u16 f2bf(float f) {
  unsigned u = __float_as_uint(f);
  u = u + 0x7fffu + ((u >> 16) & 1u);   // RNE
  return (u16)(u >> 16);
}
__device__ __forceinline__ unsigned cvtpk(float a, float b) {  // low = bf16(a), high = bf16(b), HW RNE
  unsigned r;
  asm("v_cvt_pk_bf16_f32 %0, %1, %2" : "=v"(r) : "v"(a), "v"(b));
  return r;
}
__device__ __forceinline__ float lo16(unsigned v) { return __uint_as_float(v << 16); }
__device__ __forceinline__ float hi16(unsigned v) { return __uint_as_float(v & 0xffff0000u); }

// ---------------- prep: W[k][n] f32 -> Wt[n][k] bf16 (3 weights via blockIdx.z) ----------------
__global__ void wtrans3(const float* __restrict__ Wq, const float* __restrict__ Wk,
                        const float* __restrict__ Wv,
                        u16* __restrict__ Wtq, u16* __restrict__ Wtk, u16* __restrict__ Wtv) {
  int z = blockIdx.z;
  const float* W = (z == 0) ? Wq : (z == 1) ? Wk : Wv;
  u16* Wt = (z == 0) ? Wtq : (z == 1) ? Wtk : Wtv;
  __shared__ float T[32][33];
  int k0 = blockIdx.y * 32, n0 = blockIdx.x * 32;
  int tx = threadIdx.x, ty = threadIdx.y;       // (32,8)
  #pragma unroll
  for (int j = 0; j < 4; ++j) T[ty + 8*j][tx] = W[(size_t)(k0 + ty + 8*j) * 1024 + n0 + tx];
  __syncthreads();
  #pragma unroll
  for (int j = 0; j < 4; ++j) Wt[(size_t)(n0 + ty + 8*j) * 1024 + k0 + tx] = f2bf(T[tx][ty + 8*j]);
}

// ---------------- QKV projection GEMM (1D grid, XCD-aware decode) — R20 best config ----------------
// Fused f32->bf16 A-conversion, 2-deep A prefetch (xaE/xaO), chunk-swizzled LDS,
// B via global_load_lds. grid 1536 = 8 xcd x 24 (z,y) x 8 n-blocks; z==2 writes V^T.
__global__ __launch_bounds__(256) void qkv_gemm3(const float* __restrict__ S1, const float* __restrict__ S2,
                                                 const u16* __restrict__ Wtq, const u16* __restrict__ Wtk,
                                                 const u16* __restrict__ Wtv,
                                                 const float* __restrict__ bq, const float* __restrict__ bk,
                                                 const float* __restrict__ bv,
                                                 u16* __restrict__ Qo, u16* __restrict__ Ko, u16* __restrict__ Vo) {
  int bid = blockIdx.x;
  int xcd = bid & 7, idx = bid >> 3;
  int nblk = idx & 7, pair = idx >> 3;
  int zy = xcd * 24 + pair;          // [0,192): 24 (z,y) pairs per XCD
  int z = zy >> 6, y = zy & 63;
  int m0 = y * 128, n0 = nblk * 128;

  const float* Xf  = (z == 0) ? S1 : S2;
  const u16* Wt  = (z == 0) ? Wtq : (z == 1) ? Wtk : Wtv;
  const float* bias = (z == 0) ? bq : (z == 1) ? bk : bv;
  u16* outp = (z == 0) ? Qo : (z == 1) ? Ko : Vo;

  __shared__ __align__(16) u16 As[2][128 * 32];
  __shared__ __align__(16) u16 Bs[2][128 * 32];
  int tid = threadIdx.x;
  int w = tid >> 6, l = tid & 63;
  int wm = w >> 1, wn = w & 1;
  int lq = l & 15, g = l >> 4;
  const int4* Ws = (const int4*)Wt;

  // A chunk descriptors: dest chunk i_=(row_, c of 4); src k-chunk = c ^ F(row_), F=(row_>>1)&3
  const float4* aSrc[2]; int aDst[2];
  #pragma unroll
  for (int c_ = 0; c_ < 2; ++c_) {
    int i_ = c_ * 256 + tid;
    int row_ = i_ >> 2, kc_ = (i_ & 3) ^ ((row_ >> 1) & 3);
    aSrc[c_] = (const float4*)(Xf + (size_t)(m0 + row_) * 1024 + kc_ * 8);   // advance kt*8 float4s
    aDst[c_] = i_;
  }

#define BSTAGE(bi, kt) do { _Pragma("unroll")                                                \
    for (int c_ = 0; c_ < 2; ++c_) {                                                        \
      int i_ = c_ * 256 + tid;                                                              \
      int row_ = i_ >> 2, kc_ = (i_ & 3) ^ ((row_ >> 1) & 3);                               \
      __builtin_amdgcn_global_load_lds(                                                     \
          (const __attribute__((address_space(1))) void*)&Ws[(size_t)(n0 + row_) * 128 + (kt) * 4 + kc_], \
          (__attribute__((address_space(3))) void*)&((int4*)Bs[bi])[i_], 16, 0, 0);         \
    } } while (0)

#define ALOAD(buf, kt) do { _Pragma("unroll")                                               \
    for (int c_ = 0; c_ < 2; ++c_) {                                                        \
      buf[c_][0] = aSrc[c_][(kt) * 8];                                                      \
      buf[c_][1] = aSrc[c_][(kt) * 8 + 1];                                                  \
    } } while (0)

#define AWRITE(bi, buf) do { _Pragma("unroll")                                              \
    for (int c_ = 0; c_ < 2; ++c_) {                                                        \
      u32x4 pk_;                                                                            \
      pk_[0] = cvtpk(buf[c_][0].x, buf[c_][0].y);                                           \
      pk_[1] = cvtpk(buf[c_][0].z, buf[c_][0].w);                                           \
      pk_[2] = cvtpk(buf[c_][1].x, buf[c_][1].y);                                           \
      pk_[3] = cvtpk(buf[c_][1].z, buf[c_][1].w);                                           \
      *(u32x4*)&As[bi][aDst[c_] * 8] = pk_;                                                 \
    } } while (0)

#define MFMA16(bi) do {                                                                     \
    bf16x8 a_[4], bb_[4];                                                                   \
    _Pragma("unroll")                                                                       \
    for (int mc = 0; mc < 4; ++mc) a_[mc]  = *(const bf16x8*)&As[bi][aOff[mc]];             \
    _Pragma("unroll")                                                                       \
    for (int nc = 0; nc < 4; ++nc) bb_[nc] = *(const bf16x8*)&Bs[bi][bOff[nc]];             \
    _Pragma("unroll")                                                                       \
    for (int mc = 0; mc < 4; ++mc)                                                          \
      _Pragma("unroll")                                                                     \
      for (int nc = 0; nc < 4; ++nc)                                                        \
        acc[mc][nc] = __builtin_amdgcn_mfma_f32_16x16x32_bf16(a_[mc], bb_[nc], acc[mc][nc], 0, 0, 0); \
  } while (0)

  // hoisted swizzled read offsets: row's global chunk g lives at LDS chunk g^F(row)
  int aOff[4], bOff[4];
  #pragma unroll
  for (int mc = 0; mc < 4; ++mc) {
    int rowA = wm * 64 + mc * 16 + lq;
    aOff[mc] = rowA * 32 + ((g ^ ((rowA >> 1) & 3)) * 8);
    int rowB = wn * 64 + mc * 16 + lq;
    bOff[mc] = rowB * 32 + ((g ^ ((rowB >> 1) & 3)) * 8);
  }

  f32x4 acc[4][4] = {};
  float4 xaE[2][2], xaO[2][2];
  // prologue: load tiles 0 (xaE) and 1 (xaO); write tile 0; stage B tile 0
  ALOAD(xaE, 0);
  ALOAD(xaO, 1);
  AWRITE(0, xaE);
  BSTAGE(0, 0);
  __syncthreads();

  for (int kt = 0; kt < 32; kt += 2) {
    // even step kt: compute As[0]/Bs[0]
    BSTAGE(1, kt + 1);                       // B tile kt+1 (1-step cover)
    if (kt + 2 < 32) ALOAD(xaE, kt + 2);     // A tile kt+2 (2-step cover)
    MFMA16(0);
    AWRITE(1, xaO);                          // A tile kt+1 -> As[1] (loaded 1.5 steps ago)
    __syncthreads();
    // odd step kt+1: compute As[1]/Bs[1]
    if (kt + 2 < 32) BSTAGE(0, kt + 2);
    if (kt + 3 < 32) ALOAD(xaO, kt + 3);
    MFMA16(1);
    if (kt + 2 < 32) AWRITE(0, xaE);
    __syncthreads();
  }
#undef BSTAGE
#undef ALOAD
#undef AWRITE
#undef MFMA16
  #pragma unroll
  for (int nc = 0; nc < 4; ++nc) {
    int n = n0 + wn * 64 + nc * 16 + lq;
    float bvv = bias[n];
    int h = n >> 6, d = n & 63;
    #pragma unroll
    for (int mc = 0; mc < 4; ++mc) {
      int srow_base = m0 + wm * 64 + mc * 16 + g * 4;
      if (z == 2) {
        int b = srow_base >> 10, s = srow_base & 1023;   // srow_base % 4 == 0, no b-crossing in r
        ushort4 vv;
        vv.x = f2bf(acc[mc][nc][0] + bvv);
        vv.y = f2bf(acc[mc][nc][1] + bvv);
        vv.z = f2bf(acc[mc][nc][2] + bvv);
        vv.w = f2bf(acc[mc][nc][3] + bvv);
        *(ushort4*)&outp[((size_t)((b * 16 + h) * 64 + d)) * 1024 + s] = vv;
      } else {
        #pragma unroll
        for (int r = 0; r < 4; ++r) {
          int sm = srow_base + r;
          int b = sm >> 10, s = sm & 1023;
          outp[((size_t)((b * 16 + h) * 1024 + s)) * 64 + d] = f2bf(acc[mc][nc][r] + bvv);
        }
      }
    }
  }
}

// ---------------- fused double-softmax attention, v16 (frozen, passing — R20 best config) ----------------
// = verified v13 + one barrier before the redF overlay (redF = 26112 B spans
// KVl[0] into KVl[1]). Scalar Z1/Z2 sums.
__global__ __launch_bounds__(256, 2) void attn16(const u16* __restrict__ Q, const u16* __restrict__ K,
                                                 const u16* __restrict__ Vt, const float* __restrict__ mask,
                                                 const int* __restrict__ clp, float* __restrict__ out) {
  __shared__ __align__(16) u16 KVl[2][8192];   // pass A: K dbuf; pass B: V dbuf; epilogue: redF
  __shared__ __align__(16) float maskL2[1024]; // mask * log2e
  __shared__ float z1p[4][32];
  __shared__ float z2p[4][32];

  int bid = blockIdx.x;
  int xcd = bid & 7, idx = bid >> 3;
  int bh = xcd * 16 + (idx >> 5);   // 32 q-tile blocks share (b,h) within an XCD
  int qt = idx & 31;
  int b = bh >> 4, h = bh & 15;
  int tid = threadIdx.x;
  int w = tid >> 6, l = tid & 63;
  int lq = l & 15, g = l >> 4;
  int qb = qt * 32;

  const u16* Kb = K + (size_t)bh * 65536;
  const u16* Vb = Vt + (size_t)bh * 65536;
  int cl = clp[0];

  // ---- hoisted staging addresses (affine in t) ----
  const u16* kS[4]; int kD[4];
  #pragma unroll
  for (int c_ = 0; c_ < 4; ++c_) {
    int i_ = c_ * 256 + tid, row_ = i_ >> 3, ch_ = i_ & 7;
    int f_ = (row_ & 3) | ((((row_ >> 3) ^ (row_ >> 4)) & 1) << 2);
    kS[c_] = Kb + row_ * 64 + (ch_ ^ f_) * 8;
    kD[c_] = i_ * 8;
  }
  const u16* vS[4]; int vD[4];
  #pragma unroll
  for (int c_ = 0; c_ < 4; ++c_) {
    int i_ = c_ * 256 + tid, row_ = i_ >> 4, ch_ = i_ & 15;
    vS[c_] = Vb + row_ * 1024 + (ch_ ^ (row_ & 15)) * 8;
    vD[c_] = i_ * 8;
  }

#define STAGE_K(bi, t) do { _Pragma("unroll")                                                 \
    for (int c_ = 0; c_ < 4; ++c_)                                                           \
      __builtin_amdgcn_global_load_lds(                                                      \
        (const __attribute__((address_space(1))) void*)(kS[c_] + (t) * 8192),                \
        (__attribute__((address_space(3))) void*)&KVl[bi][kD[c_]], 16, 0, 0); } while (0)

#define STAGE_V(bi, t) do { _Pragma("unroll")                                                 \
    for (int c_ = 0; c_ < 4; ++c_)                                                           \
      __builtin_amdgcn_global_load_lds(                                                      \
        (const __attribute__((address_space(1))) void*)(vS[c_] + (t) * 128),                 \
        (__attribute__((address_space(3))) void*)&KVl[bi][vD[c_]], 16, 0, 0); } while (0)

  STAGE_K(0, 0);

  for (int i = tid; i < 1024; i += 256) maskL2[i] = mask[b * 1024 + i] * L2E;

  // Q fragments: 32 rows (qg 0,1)
  bf16x8 qf[2][2];
  #pragma unroll
  for (int qg = 0; qg < 2; ++qg) {
    const u16* Qp = Q + ((size_t)bh * 1024 + qb + qg * 16 + lq) * 64 + g * 8;
    qf[qg][0] = *(const bf16x8*)Qp;
    qf[qg][1] = *(const bf16x8*)(Qp + 32);
  }

  // ---- hoisted LDS read offsets (lane-constant) ----
  int kOff[2][2];
  #pragma unroll
  for (int c = 0; c < 2; ++c) {
    int row128 = w * 32 + ((lq >> 2) << 3) + c * 4 + (lq & 3);   // kappa(A-row = lq)
    int F = (row128 & 3) | ((((row128 >> 3) ^ (row128 >> 4)) & 1) << 2);
    kOff[c][0] = row128 * 64 + ((g ^ F) * 8);
    kOff[c][1] = row128 * 64 + (((g + 4) ^ F) * 8);
  }
  int vOff[4];
  #pragma unroll
  for (int dc = 0; dc < 4; ++dc) {
    int row = dc * 16 + lq;
    vOff[dc] = row * 128 + (((w * 4 + g) ^ (row & 15)) * 8);
  }
  int mBase = w * 32 + g * 8;   // mask index = t*128 + mBase + c*4

  __syncthreads();   // K0 staged + maskL2 ready

  // ---- pass A: swapped QK^T (quarter x 32q), E = exp2(s+mkl) packed to sp[64], Z1 ----
  const float sl2e = 0.125f * L2E;
  unsigned sp[64];
  float z1[2] = {0.f, 0.f};
  int cur = 0;
  #pragma unroll
  for (int t = 0; t < 8; ++t) {
    if (t < 7) STAGE_K(cur ^ 1, t + 1);
    else       STAGE_V(0, 0);            // prefetch pass-B V tile 0 (KVl[0] dead: cur==1 at t=7)
    #pragma unroll
    for (int c = 0; c < 2; ++c) {
      bf16x8 kf0 = *(const bf16x8*)&KVl[cur][kOff[c][0]];
      bf16x8 kf1 = *(const bf16x8*)&KVl[cur][kOff[c][1]];
      const float4 mk = *(const float4*)&maskL2[t * 128 + mBase + c * 4];
      #pragma unroll
      for (int qg = 0; qg < 2; ++qg) {
        f32x4 tt = {0.f, 0.f, 0.f, 0.f};
        tt = __builtin_amdgcn_mfma_f32_16x16x32_bf16(kf0, qf[qg][0], tt, 0, 0, 0);
        tt = __builtin_amdgcn_mfma_f32_16x16x32_bf16(kf1, qf[qg][1], tt, 0, 0, 0);
        float e0 = __builtin_amdgcn_exp2f(fmaf(tt[0], sl2e, mk.x));
        float e1 = __builtin_amdgcn_exp2f(fmaf(tt[1], sl2e, mk.y));
        float e2 = __builtin_amdgcn_exp2f(fmaf(tt[2], sl2e, mk.z));
        float e3 = __builtin_amdgcn_exp2f(fmaf(tt[3], sl2e, mk.w));
        z1[qg] += (e0 + e1) + (e2 + e3);
        sp[t * 8 + qg * 4 + c * 2 + 0] = cvtpk(e0, e1);
        sp[t * 8 + qg * 4 + c * 2 + 1] = cvtpk(e2, e3);
      }
    }
    __syncthreads();
    cur ^= 1;
  }

  // ---- merge Z1: g-groups (shfl) + 4 waves (LDS) -> cr[qg] = L2E / Z1 ----
  #pragma unroll
  for (int qg = 0; qg < 2; ++qg) {
    z1[qg] += __shfl_xor(z1[qg], 16);
    z1[qg] += __shfl_xor(z1[qg], 32);
  }
  if (l < 16) { z1p[w][l] = z1[0]; z1p[w][16 + l] = z1[1]; }
  __syncthreads();
  float cr[2];
  #pragma unroll
  for (int qg = 0; qg < 2; ++qg) {
    int q = qg * 16 + lq;
    float Z1 = (z1p[0][q] + z1p[1][q]) + (z1p[2][q] + z1p[3][q]);
    cr[qg] = L2E * __builtin_amdgcn_rcpf(Z1);
  }

  // ---- pass B: p2 = exp2(mkl - cr*E), PV over V dbuf (tile t in KVl[t&1]) ----
  f32x4 acc[2][4] = {};
  float z2[2] = {0.f, 0.f};
  #pragma unroll
  for (int t = 0; t < 8; ++t) {
    if (t < 7) STAGE_V((t + 1) & 1, t + 1);
    u32x4 pk[2];
    #pragma unroll
    for (int qg = 0; qg < 2; ++qg) {
      if (cl) {
        #pragma unroll
        for (int j = 0; j < 4; ++j) {
          unsigned e = sp[t * 8 + qg * 4 + j];
          float mkA = maskL2[t * 128 + mBase + 2 * j];
          float mkB = maskL2[t * 128 + mBase + 2 * j + 1];
          float pA = __builtin_amdgcn_exp2f(fmaf(-cr[qg], lo16(e), mkA));
          float pB = __builtin_amdgcn_exp2f(fmaf(-cr[qg], hi16(e), mkB));
          z2[qg] += pA + pB;
          pk[qg][j] = cvtpk(pA, pB);
        }
      } else {
        pk[qg] = *(u32x4*)&sp[t * 8 + qg * 4];   // unnormalized E; epilogue scales by 1/Z1
      }
    }
    #pragma unroll
    for (int dc = 0; dc < 4; ++dc) {
      bf16x8 vf = *(const bf16x8*)&KVl[t & 1][vOff[dc]];
      #pragma unroll
      for (int qg = 0; qg < 2; ++qg)
        acc[qg][dc] = __builtin_amdgcn_mfma_f32_16x16x32_bf16(
            __builtin_bit_cast(bf16x8, pk[qg]), vf, acc[qg][dc], 0, 0, 0);
    }
    if (t < 7) __syncthreads();            // tile t reads done + tile t+1 staged/visible
  }

  // ---- epilogue: 4-way Z2 merge + 4-way acc reduction through dead KVl ----
  #pragma unroll
  for (int qg = 0; qg < 2; ++qg) {
    z2[qg] += __shfl_xor(z2[qg], 16);
    z2[qg] += __shfl_xor(z2[qg], 32);
  }
  if (l < 16) { z2p[w][l] = z2[0]; z2p[w][16 + l] = z2[1]; }
  __syncthreads();   // all waves' V-tile-7 reads (KVl[1]) complete before redF
                     // (26112 B, spans KVl[0]+into KVl[1]) is written.
  float* redF = (float*)&KVl[0][0];    // [3][32 q][68 d-stride]
  if (w > 0) {
    #pragma unroll
    for (int qg = 0; qg < 2; ++qg)
      #pragma unroll
      for (int dc = 0; dc < 4; ++dc)
        #pragma unroll
        for (int r = 0; r < 4; ++r)
          redF[(w - 1) * 2176 + (qg * 16 + g * 4 + r) * 68 + dc * 16 + lq] = acc[qg][dc][r];
  }
  __syncthreads();
  if (w == 0) {
    #pragma unroll
    for (int qg = 0; qg < 2; ++qg) {
      #pragma unroll
      for (int r = 0; r < 4; ++r) {
        int q = qg * 16 + g * 4 + r;
        float phi;
        if (cl) {
          float Z2 = (z2p[0][q] + z2p[1][q]) + (z2p[2][q] + z2p[3][q]);
          phi = __builtin_amdgcn_rcpf(Z2);
        } else {
          float Z1 = (z1p[0][q] + z1p[1][q]) + (z1p[2][q] + z1p[3][q]);
          phi = __builtin_amdgcn_rcpf(Z1);
        }
        size_t orow = ((size_t)(b * 1024 + qb + q)) * 1024 + h * 64;
        #pragma unroll
        for (int dc = 0; dc < 4; ++dc) {
          int dq = q * 68 + dc * 16 + lq;
          float o = acc[qg][dc][r] + redF[dq] + redF[2176 + dq] + redF[4352 + dq];
          out[orow + dc * 16 + lq] = o * phi;
        }
      }
    }
  }
#undef STAGE_K
#undef STAGE_V
}

extern "C" void kernel_launch(void* const* d_in, const int* in_sizes, int n_in,
                              void* d_out, int out_size, void* d_ws, size_t ws_size,
                              hipStream_t stream) {
  const float* s1   = (const float*)d_in[0];
  const float* s2   = (const float*)d_in[1];
  const float* mask = (const float*)d_in[2];
  const float* Wq   = (const float*)d_in[3];
  const float* bq   = (const float*)d_in[4];
  const float* Wk   = (const float*)d_in[5];
  const float* bk   = (const float*)d_in[6];
  const float* Wv   = (const float*)d_in[7];
  const float* bv   = (const float*)d_in[8];
  const int*   cl   = (const int*)d_in[9];
  float* out = (float*)d_out;

  // ws layout (u16 elements): [unused 16M] Wtq[1M] Wtk[1M] Wtv[1M] Q[8M] K[8M] Vt[8M]
  u16* ws  = (u16*)d_ws;
  const size_t M1 = 1024 * 1024;
  u16* Wtq = ws + 16 * M1;
  u16* Wtk = Wtq + M1;
  u16* Wtv = Wtk + M1;
  u16* Qb  = Wtv + M1;
  u16* Kb  = Qb + 8 * M1;
  u16* Vtb = Kb + 8 * M1;        // V^T written directly by qkv_gemm3 (z==2)

  wtrans3<<<dim3(32, 32, 3), dim3(32, 8), 0, stream>>>(Wq, Wk, Wv, Wtq, Wtk, Wtv);
  qkv_gemm3<<<1536, 256, 0, stream>>>(s1, s2, Wtq, Wtk, Wtv, bq, bk, bv, Qb, Kb, Vtb);
  attn16<<<4096, 256, 0, stream>>>(Qb, Kb, Vtb, mask, cl, out);
}